// Round 2
// baseline (1168.043 us; speedup 1.0000x reference)
//
#include <hip/hip_runtime.h>
#include <stdint.h>

typedef _Float16 h2 __attribute__((ext_vector_type(2)));
typedef _Float16 h8 __attribute__((ext_vector_type(8)));
typedef float f32x4 __attribute__((ext_vector_type(4)));

#define LDK 40  // padded LDS k-stride in f16 elements (80 B = 20 banks -> 2-way, free)

__device__ __forceinline__ uint32_t pk_cvt(float a, float b) {
  return __builtin_bit_cast(uint32_t, __builtin_amdgcn_cvt_pkrtz(a, b));
}

__device__ __forceinline__ uint32_t dq(uint32_t t, h2 z2, h2 s2) {
  // t holds two f16 values (1024+n_lo, 1024+n_hi); subtract exact integer
  // (1025+zp) in f16 (exact: integers < 2048), then scale (single rounding).
  h2 v = __builtin_bit_cast(h2, t);
  h2 w = (v - z2) * s2;
  return __builtin_bit_cast(uint32_t, w);
}

__global__ __launch_bounds__(256) void gptq_gemm_kernel(
    const float* __restrict__ x,
    const uint32_t* __restrict__ qweight,
    const uint32_t* __restrict__ qzeros,
    const float* __restrict__ scales,
    const float* __restrict__ bias,
    float* __restrict__ out,
    int M, int N, int K) {
  __shared__ _Float16 As[128 * LDK];
  __shared__ _Float16 Bs[128 * LDK];

  const int tid = threadIdx.x;
  const int lane = tid & 63;
  const int wave = tid >> 6;
  const int wm = wave & 1;         // wave row (x64)
  const int wn = wave >> 1;        // wave col (x64)
  const int bn0 = blockIdx.x * 128;
  const int bm0 = blockIdx.y * 128;

  // staging map: thread t covers (row sr, k-groups sg0, sg0+1) for both A and B
  const int sr = tid >> 1;         // 0..127
  const int sg0 = (tid & 1) * 2;   // 0 or 2

  const float* xrow = x + (size_t)(bm0 + sr) * K + sg0 * 8;
  const int colb = bn0 + sr;       // B staging column (output feature)
  const int groups = K >> 7;       // K / 128
  const int NP = N >> 3;           // qzeros row stride (int32 words)

  f32x4 acc[4][4];
#pragma unroll
  for (int i = 0; i < 4; ++i)
#pragma unroll
    for (int j = 0; j < 4; ++j) acc[i][j] = (f32x4)0.f;

  // MFMA fragment LDS base addrs: lane holds A[m=lane&15][k=(lane>>4)*8+j]
  const _Float16* Ab = As + (wm * 64 + (lane & 15)) * LDK + (lane >> 4) * 8;
  const _Float16* Bb = Bs + (wn * 64 + (lane & 15)) * LDK + (lane >> 4) * 8;

  for (int g = 0; g < groups; ++g) {
    // per-group dequant constants for this thread's column
    uint32_t qz = qzeros[(size_t)g * NP + (colb >> 3)];
    int zp = (qz >> ((colb & 7) * 4)) & 15;
    float sc = scales[(size_t)g * N + colb];
    _Float16 hz = (_Float16)(float)(1024 + zp + 1);  // exact integer in f16
    _Float16 hs = (_Float16)sc;
    h2 z2 = {hz, hz};
    h2 s2 = {hs, hs};

#pragma unroll
    for (int kt = 0; kt < 4; ++kt) {
      const int k0 = g * 128 + kt * 32;
      // ---- global loads issued before the barrier (in flight across it) ----
      const float* xr = xrow + k0;
      float4 fa0 = *(const float4*)(xr);
      float4 fa1 = *(const float4*)(xr + 4);
      float4 fa2 = *(const float4*)(xr + 8);
      float4 fa3 = *(const float4*)(xr + 12);
      const size_t kp = (size_t)(k0 >> 3) + sg0;
      uint32_t q0 = qweight[kp * N + colb];
      uint32_t q1 = qweight[(kp + 1) * N + colb];

      __syncthreads();  // previous iteration's fragment reads complete

      // ---- A: fp32 -> f16, k-permutation [0,4,1,5,2,6,3,7] per 8-group ----
      uint4 av0 = make_uint4(pk_cvt(fa0.x, fa1.x), pk_cvt(fa0.y, fa1.y),
                             pk_cvt(fa0.z, fa1.z), pk_cvt(fa0.w, fa1.w));
      uint4 av1 = make_uint4(pk_cvt(fa2.x, fa3.x), pk_cvt(fa2.y, fa3.y),
                             pk_cvt(fa2.z, fa3.z), pk_cvt(fa2.w, fa3.w));
      *(uint4*)(As + sr * LDK + sg0 * 8) = av0;
      *(uint4*)(As + sr * LDK + sg0 * 8 + 8) = av1;

      // ---- B: int4 dequant, same k-permutation (nibble pairs j, j+4) ----
      uint4 bv0 = make_uint4(dq(((q0) & 0x000F000Fu) | 0x64006400u, z2, s2),
                             dq(((q0 >> 4) & 0x000F000Fu) | 0x64006400u, z2, s2),
                             dq(((q0 >> 8) & 0x000F000Fu) | 0x64006400u, z2, s2),
                             dq(((q0 >> 12) & 0x000F000Fu) | 0x64006400u, z2, s2));
      uint4 bv1 = make_uint4(dq(((q1) & 0x000F000Fu) | 0x64006400u, z2, s2),
                             dq(((q1 >> 4) & 0x000F000Fu) | 0x64006400u, z2, s2),
                             dq(((q1 >> 8) & 0x000F000Fu) | 0x64006400u, z2, s2),
                             dq(((q1 >> 12) & 0x000F000Fu) | 0x64006400u, z2, s2));
      *(uint4*)(Bs + sr * LDK + sg0 * 8) = bv0;
      *(uint4*)(Bs + sr * LDK + sg0 * 8 + 8) = bv1;

      __syncthreads();

      // ---- fragments + 16 MFMA ----
      h8 af[4], bf[4];
#pragma unroll
      for (int i = 0; i < 4; ++i) {
        af[i] = *(const h8*)(Ab + i * 16 * LDK);
        bf[i] = *(const h8*)(Bb + i * 16 * LDK);
      }
#pragma unroll
      for (int i = 0; i < 4; ++i)
#pragma unroll
        for (int j = 0; j < 4; ++j)
          acc[i][j] = __builtin_amdgcn_mfma_f32_16x16x32_f16(af[i], bf[j],
                                                             acc[i][j], 0, 0, 0);
    }
  }

  // ---- epilogue: D[row=(lane>>4)*4+r][col=lane&15] per 16x16 tile ----
  const int r0 = bm0 + wm * 64 + (lane >> 4) * 4;
  const int c0 = bn0 + wn * 64 + (lane & 15);
#pragma unroll
  for (int j = 0; j < 4; ++j) {
    const int c = c0 + j * 16;
    const float bv = bias[c];
#pragma unroll
    for (int i = 0; i < 4; ++i) {
#pragma unroll
      for (int rr = 0; rr < 4; ++rr) {
        out[(size_t)(r0 + i * 16 + rr) * N + c] = acc[i][j][rr] + bv;
      }
    }
  }
}

extern "C" void kernel_launch(void* const* d_in, const int* in_sizes, int n_in,
                              void* d_out, int out_size, void* d_ws, size_t ws_size,
                              hipStream_t stream) {
  const float* x = (const float*)d_in[0];
  const uint32_t* qweight = (const uint32_t*)d_in[1];
  const uint32_t* qzeros = (const uint32_t*)d_in[2];
  const float* scales = (const float*)d_in[3];
  const float* bias = (const float*)d_in[4];
  float* out = (float*)d_out;

  const int out_f = in_sizes[4];                 // 11008
  const int groups = in_sizes[3] / out_f;        // 32
  const int in_f = groups * 128;                 // 4096
  const int tokens = in_sizes[0] / in_f;         // 4096

  dim3 grid(out_f / 128, tokens / 128);          // 86 x 32
  gptq_gemm_kernel<<<grid, 256, 0, stream>>>(x, qweight, qzeros, scales, bias,
                                             out, tokens, out_f, in_f);
}

// Round 3
// 827.729 us; speedup vs baseline: 1.4111x; 1.4111x over previous
//
#include <hip/hip_runtime.h>
#include <stdint.h>

typedef _Float16 h2 __attribute__((ext_vector_type(2)));
typedef _Float16 h8 __attribute__((ext_vector_type(8)));
typedef float f32x4 __attribute__((ext_vector_type(4)));

__device__ __forceinline__ uint32_t pk_cvt(float a, float b) {
  return __builtin_bit_cast(uint32_t, __builtin_amdgcn_cvt_pkrtz(a, b));
}

__device__ __forceinline__ uint32_t dq(uint32_t t, h2 z2, h2 s2) {
  // t = two f16 (1024+n_lo, 1024+n_hi); exact integer subtract, one rounded mul
  h2 v = __builtin_bit_cast(h2, t);
  h2 w = (v - z2) * s2;
  return __builtin_bit_cast(uint32_t, w);
}

__device__ __forceinline__ uint32_t dq_lin(uint32_t u, h2 z2, h2 s2) {
  // nibbles at bits 0-3 and 4-7 of u -> linear pair (k, k+1)
  uint32_t t = (u & 0xFu) | ((u & 0xF0u) << 12) | 0x64006400u;
  return dq(t, z2, s2);
}

typedef __attribute__((address_space(1))) const uint32_t* gas_ptr;
typedef __attribute__((address_space(3))) uint32_t* las_ptr;
__device__ __forceinline__ void gll16(const _Float16* g, _Float16* l) {
  // lane i lands at l + i*16B (wave-uniform base); 16B per lane
  __builtin_amdgcn_global_load_lds((gas_ptr)g, (las_ptr)l, 16, 0, 0);
}

// ---------------- phase 1: x fp32 -> f16 (linear k order) ----------------
__global__ __launch_bounds__(256) void cvt_x_kernel(const float* __restrict__ x,
                                                    _Float16* __restrict__ xh,
                                                    size_t n) {
  size_t i = ((size_t)blockIdx.x * 256 + threadIdx.x) * 8;
  if (i >= n) return;
  float4 a = *(const float4*)(x + i);
  float4 b = *(const float4*)(x + i + 4);
  uint4 v = make_uint4(pk_cvt(a.x, a.y), pk_cvt(a.z, a.w),
                       pk_cvt(b.x, b.y), pk_cvt(b.z, b.w));
  *(uint4*)(xh + i) = v;
}

// -------- phase 2: dequant qweight -> W^T f16 [N][K], linear k ----------
__global__ __launch_bounds__(256) void dequant_w_kernel(
    const uint32_t* __restrict__ qweight, const uint32_t* __restrict__ qzeros,
    const float* __restrict__ scales, _Float16* __restrict__ wt, int N, int K) {
  __shared__ uint32_t qw[8][64];
  const int t = threadIdx.x;
  const int n0 = blockIdx.x * 64;
  const int kp0 = blockIdx.y * 8;  // 8 packed words = 64 k, inside one group

  {  // coalesced load of the [8 kp][64 n] tile
    int r = t >> 6, c = t & 63;
    qw[r][c]     = qweight[(size_t)(kp0 + r) * N + n0 + c];
    qw[r + 4][c] = qweight[(size_t)(kp0 + r + 4) * N + n0 + c];
  }
  __syncthreads();

  const int nl = t >> 2;           // output row (column of W) 0..63
  const int kpl = (t & 3) * 2;     // this thread's 2 packed words
  const int n = n0 + nl;
  const int g = kp0 >> 4;          // group = k/128 = kp/16
  uint32_t qz = qzeros[(size_t)g * (N >> 3) + (n >> 3)];
  int zp = (qz >> ((n & 7) * 4)) & 15;
  float sc = scales[(size_t)g * N + n];
  _Float16 hz = (_Float16)(float)(1024 + zp + 1);
  _Float16 hs = (_Float16)sc;
  h2 z2 = {hz, hz};
  h2 s2 = {hs, hs};

#pragma unroll
  for (int w = 0; w < 2; ++w) {
    uint32_t word = qw[kpl + w][nl];
    uint4 v = make_uint4(dq_lin(word, z2, s2), dq_lin(word >> 8, z2, s2),
                         dq_lin(word >> 16, z2, s2), dq_lin(word >> 24, z2, s2));
    *(uint4*)(wt + (size_t)n * K + (size_t)(kp0 + kpl + w) * 8) = v;
  }
}

// ------------- phase 3: f16 GEMM, m97 structure (global_load_lds) -------
__global__ __launch_bounds__(256) void gemm_f16_kernel(
    const _Float16* __restrict__ A,   // [M][K] f16
    const _Float16* __restrict__ B,   // [N][K] f16 (W^T)
    const float* __restrict__ bias, float* __restrict__ out,
    int M, int N, int K) {
  __shared__ _Float16 As[128 * 32];   // unpadded: required by global_load_lds
  __shared__ _Float16 Bs[128 * 32];

  const int tid = threadIdx.x;
  const int lane = tid & 63;
  const int wave = tid >> 6;
  const int wm = wave & 1;
  const int wn = wave >> 1;
  const int bn0 = blockIdx.x * 128;
  const int bm0 = blockIdx.y * 128;

  f32x4 acc[4][4];
#pragma unroll
  for (int i = 0; i < 4; ++i)
#pragma unroll
    for (int j = 0; j < 4; ++j) acc[i][j] = (f32x4)0.f;

  // staging: wave w covers rows [w*16, w*16+16) and [64+w*16, ...)
  // lane i: row += i>>2, 16B chunk (i&3) within the 64B row
  const int srow = wave * 16 + (lane >> 2);
  const int skoff = (lane & 3) * 8;
  const _Float16* Ag0 = A + (size_t)(bm0 + srow) * K + skoff;
  const _Float16* Ag1 = A + (size_t)(bm0 + 64 + srow) * K + skoff;
  const _Float16* Bg0 = B + (size_t)(bn0 + srow) * K + skoff;
  const _Float16* Bg1 = B + (size_t)(bn0 + 64 + srow) * K + skoff;
  _Float16* Al0 = As + (wave * 16) * 32;
  _Float16* Al1 = As + (64 + wave * 16) * 32;
  _Float16* Bl0 = Bs + (wave * 16) * 32;
  _Float16* Bl1 = Bs + (64 + wave * 16) * 32;

  // fragment bases: A[m=lane&15][k=(lane>>4)*8+j]
  const _Float16* Af = As + (wm * 64 + (lane & 15)) * 32 + (lane >> 4) * 8;
  const _Float16* Bf = Bs + (wn * 64 + (lane & 15)) * 32 + (lane >> 4) * 8;

  for (int k0 = 0; k0 < K; k0 += 32) {
    gll16(Ag0 + k0, Al0);
    gll16(Ag1 + k0, Al1);
    gll16(Bg0 + k0, Bl0);
    gll16(Bg1 + k0, Bl1);
    __syncthreads();  // drains vmcnt(0): LDS tiles complete + visible

    h8 af[4], bf[4];
#pragma unroll
    for (int i = 0; i < 4; ++i) {
      af[i] = *(const h8*)(Af + i * 16 * 32);
      bf[i] = *(const h8*)(Bf + i * 16 * 32);
    }
#pragma unroll
    for (int i = 0; i < 4; ++i)
#pragma unroll
      for (int j = 0; j < 4; ++j)
        acc[i][j] = __builtin_amdgcn_mfma_f32_16x16x32_f16(af[i], bf[j],
                                                           acc[i][j], 0, 0, 0);
    __syncthreads();  // fragment reads done before next staging overwrites
  }

  // epilogue: D[row=(lane>>4)*4+r][col=lane&15] per 16x16 tile (verified r2)
  const int r0 = bm0 + wm * 64 + (lane >> 4) * 4;
  const int c0 = bn0 + wn * 64 + (lane & 15);
#pragma unroll
  for (int j = 0; j < 4; ++j) {
    const int c = c0 + j * 16;
    const float bv = bias[c];
#pragma unroll
    for (int i = 0; i < 4; ++i) {
#pragma unroll
      for (int rr = 0; rr < 4; ++rr) {
        out[(size_t)(r0 + i * 16 + rr) * N + c] = acc[i][j][rr] + bv;
      }
    }
  }
}

// ------------------- fallback: round-2 fused kernel ---------------------
#define LDK 40
__global__ __launch_bounds__(256) void gptq_gemm_fused(
    const float* __restrict__ x, const uint32_t* __restrict__ qweight,
    const uint32_t* __restrict__ qzeros, const float* __restrict__ scales,
    const float* __restrict__ bias, float* __restrict__ out,
    int M, int N, int K) {
  __shared__ _Float16 As[128 * LDK];
  __shared__ _Float16 Bs[128 * LDK];
  const int tid = threadIdx.x, lane = tid & 63, wave = tid >> 6;
  const int wm = wave & 1, wn = wave >> 1;
  const int bn0 = blockIdx.x * 128, bm0 = blockIdx.y * 128;
  const int sr = tid >> 1, sg0 = (tid & 1) * 2;
  const float* xrow = x + (size_t)(bm0 + sr) * K + sg0 * 8;
  const int colb = bn0 + sr;
  const int groups = K >> 7, NP = N >> 3;
  f32x4 acc[4][4];
#pragma unroll
  for (int i = 0; i < 4; ++i)
#pragma unroll
    for (int j = 0; j < 4; ++j) acc[i][j] = (f32x4)0.f;
  const _Float16* Ab = As + (wm * 64 + (lane & 15)) * LDK + (lane >> 4) * 8;
  const _Float16* Bb = Bs + (wn * 64 + (lane & 15)) * LDK + (lane >> 4) * 8;
  for (int g = 0; g < groups; ++g) {
    uint32_t qz = qzeros[(size_t)g * NP + (colb >> 3)];
    int zp = (qz >> ((colb & 7) * 4)) & 15;
    float sc = scales[(size_t)g * N + colb];
    _Float16 hz = (_Float16)(float)(1024 + zp + 1);
    _Float16 hs = (_Float16)sc;
    h2 z2 = {hz, hz}, s2 = {hs, hs};
#pragma unroll
    for (int kt = 0; kt < 4; ++kt) {
      const int k0 = g * 128 + kt * 32;
      const float* xr = xrow + k0;
      float4 fa0 = *(const float4*)(xr);
      float4 fa1 = *(const float4*)(xr + 4);
      float4 fa2 = *(const float4*)(xr + 8);
      float4 fa3 = *(const float4*)(xr + 12);
      const size_t kp = (size_t)(k0 >> 3) + sg0;
      uint32_t q0 = qweight[kp * N + colb];
      uint32_t q1 = qweight[(kp + 1) * N + colb];
      __syncthreads();
      uint4 av0 = make_uint4(pk_cvt(fa0.x, fa1.x), pk_cvt(fa0.y, fa1.y),
                             pk_cvt(fa0.z, fa1.z), pk_cvt(fa0.w, fa1.w));
      uint4 av1 = make_uint4(pk_cvt(fa2.x, fa3.x), pk_cvt(fa2.y, fa3.y),
                             pk_cvt(fa2.z, fa3.z), pk_cvt(fa2.w, fa3.w));
      *(uint4*)(As + sr * LDK + sg0 * 8) = av0;
      *(uint4*)(As + sr * LDK + sg0 * 8 + 8) = av1;
      uint4 bv0 = make_uint4(dq((q0 & 0x000F000Fu) | 0x64006400u, z2, s2),
                             dq(((q0 >> 4) & 0x000F000Fu) | 0x64006400u, z2, s2),
                             dq(((q0 >> 8) & 0x000F000Fu) | 0x64006400u, z2, s2),
                             dq(((q0 >> 12) & 0x000F000Fu) | 0x64006400u, z2, s2));
      uint4 bv1 = make_uint4(dq((q1 & 0x000F000Fu) | 0x64006400u, z2, s2),
                             dq(((q1 >> 4) & 0x000F000Fu) | 0x64006400u, z2, s2),
                             dq(((q1 >> 8) & 0x000F000Fu) | 0x64006400u, z2, s2),
                             dq(((q1 >> 12) & 0x000F000Fu) | 0x64006400u, z2, s2));
      *(uint4*)(Bs + sr * LDK + sg0 * 8) = bv0;
      *(uint4*)(Bs + sr * LDK + sg0 * 8 + 8) = bv1;
      __syncthreads();
      h8 af[4], bf[4];
#pragma unroll
      for (int i = 0; i < 4; ++i) {
        af[i] = *(const h8*)(Ab + i * 16 * LDK);
        bf[i] = *(const h8*)(Bb + i * 16 * LDK);
      }
#pragma unroll
      for (int i = 0; i < 4; ++i)
#pragma unroll
        for (int j = 0; j < 4; ++j)
          acc[i][j] = __builtin_amdgcn_mfma_f32_16x16x32_f16(af[i], bf[j],
                                                             acc[i][j], 0, 0, 0);
    }
  }
  const int r0 = bm0 + wm * 64 + (lane >> 4) * 4;
  const int c0 = bn0 + wn * 64 + (lane & 15);
#pragma unroll
  for (int j = 0; j < 4; ++j) {
    const int c = c0 + j * 16;
    const float bv = bias[c];
#pragma unroll
    for (int i = 0; i < 4; ++i)
#pragma unroll
      for (int rr = 0; rr < 4; ++rr)
        out[(size_t)(r0 + i * 16 + rr) * N + c] = acc[i][j][rr] + bv;
  }
}

extern "C" void kernel_launch(void* const* d_in, const int* in_sizes, int n_in,
                              void* d_out, int out_size, void* d_ws, size_t ws_size,
                              hipStream_t stream) {
  const float* x = (const float*)d_in[0];
  const uint32_t* qweight = (const uint32_t*)d_in[1];
  const uint32_t* qzeros = (const uint32_t*)d_in[2];
  const float* scales = (const float*)d_in[3];
  const float* bias = (const float*)d_in[4];
  float* out = (float*)d_out;

  const int out_f = in_sizes[4];            // 11008
  const int groups = in_sizes[3] / out_f;   // 32
  const int in_f = groups * 128;            // 4096
  const int tokens = in_sizes[0] / in_f;    // 4096

  const size_t need = ((size_t)tokens * in_f + (size_t)out_f * in_f) * 2;
  if (ws_size >= need) {
    _Float16* xh = (_Float16*)d_ws;
    _Float16* wt = xh + (size_t)tokens * in_f;

    size_t nx = (size_t)tokens * in_f;
    cvt_x_kernel<<<(nx + 2047) / 2048, 256, 0, stream>>>(x, xh, nx);

    dim3 gq(out_f / 64, (in_f / 8) / 8);    // 172 x 64
    dequant_w_kernel<<<gq, 256, 0, stream>>>(qweight, qzeros, scales, wt,
                                             out_f, in_f);

    dim3 gg(out_f / 128, tokens / 128);     // 86 x 32
    gemm_f16_kernel<<<gg, 256, 0, stream>>>(xh, wt, bias, out,
                                            tokens, out_f, in_f);
  } else {
    dim3 grid(out_f / 128, tokens / 128);
    gptq_gemm_fused<<<grid, 256, 0, stream>>>(x, qweight, qzeros, scales, bias,
                                              out, tokens, out_f, in_f);
  }
}